// Round 4
// baseline (578.206 us; speedup 1.0000x reference)
//
#include <hip/hip_runtime.h>
#include <hip/hip_bf16.h>

// LSTMblock: 2-layer, 8-head LSTM (H=F=64, T=12) over N=16384 nodes, then
// 1x1 conv mixing (head,t) channels (96 -> 12). fp32 I/O, bf16 MFMA, fp32 cell.
//
// R8: R5-R7 shaved phase contents (store drain, VALU, LDS) for only -5%;
// floors say ~100us (pointwise) / 59us (HBM) vs 366us measured -> the phase
// STRUCTURE is latency-bound: 13 barriers per 16 nodes, one dependent
// MFMA+pointwise chain per wave per phase, 4 waves/SIMD lockstep.
// Change: MT 16 -> 32 nodes/block. Each wave runs TWO independent 16-node
// halves per phase (2x ILP, weights reused across halves, barriers per node
// halved). To fit: no xT LDS (l0 reads x frags from global/L3 at phase top),
// no h1 history (l1 stores hs per-phase from regs, R7 measured drain ~3%),
// LDS = h0A/h1A dbuf + bias = 20.5KB. Pointwise on f32x4 vectors (same math,
// packed-friendly). 4096 blocks.
//
// MFMA v_mfma_f32_16x16x32_bf16 lane mapping (m89/m120-verified):
//   A[m][k]: lane(quad,col) reg j holds A[m=col][k=quad*8+j]
//   B[k][n]: lane reg j holds B[k=quad*8+j][n=col]
//   D[m][n]: lane reg r holds D[m=quad*4+r][n=col]
// Swapped form D = W*h^T: lane holds gates for node=col at 4 consecutive
// gate-cols (wq*16 + quad*4 + r); h-write is one ds_write_b64.

#define T_LEN 12
#define NHEADS 8
#define HD 64
#define NNODES 16384
#define MT 16           // mono fallback tile
#define MTP 32          // pipe kernel tile
#define LDSP 72
#define WIH_ELEMS (2 * NHEADS * 4 * HD * HD)   // 262144 elems per weight tensor

typedef __bf16 bf16_t;
typedef __attribute__((ext_vector_type(2))) __bf16 bf16x2;
typedef __attribute__((ext_vector_type(4))) __bf16 bf16x4;
typedef __attribute__((ext_vector_type(8))) __bf16 bf16x8;
typedef __attribute__((ext_vector_type(4))) float f32x4;

#define MFMA16(a, b, c) __builtin_amdgcn_mfma_f32_16x16x32_bf16((a), (b), (c), 0, 0, 0)

#if __has_builtin(__builtin_amdgcn_exp2f)
#define EXP2(x) __builtin_amdgcn_exp2f(x)
#else
#define EXP2(x) exp2f(x)
#endif

__device__ __forceinline__ float fast_sigmoid(float v) {
    return __builtin_amdgcn_rcpf(1.0f + __expf(-v));
}
__device__ __forceinline__ float fast_tanh(float v) {
    return 2.0f * __builtin_amdgcn_rcpf(1.0f + __expf(-2.0f * v)) - 1.0f;
}

__device__ __forceinline__ bf16x8 load8f(const float* p) {
    f32x4 a = *(const f32x4*)p;
    f32x4 b = *(const f32x4*)(p + 4);
    bf16x8 r;
    r[0] = (bf16_t)a[0]; r[1] = (bf16_t)a[1]; r[2] = (bf16_t)a[2]; r[3] = (bf16_t)a[3];
    r[4] = (bf16_t)b[0]; r[5] = (bf16_t)b[1]; r[6] = (bf16_t)b[2]; r[7] = (bf16_t)b[3];
    return r;
}

// Gate pointwise for one 16-node half: lane owns node=col(+16m), hcols
// wq*16+quad*4..+3. Vector f32x4 form (rows r=0..3 in lanes of the vector)
// so mul/add pairs can pack into v_pk_*_f32. Math identical to scalar:
// 1 rcp per row for gates, 1 shared rcp for the tanh batch.
template<bool SC>
__device__ __forceinline__ bf16x4 lstm_pointwise_v(const f32x4* acc, f32x4& creg) {
    f32x4 e_i, e_f, e_g, e_o;
    #pragma unroll
    for (int r = 0; r < 4; ++r) {
        if (SC) {
            e_i[r] = EXP2(-acc[0][r]); e_f[r] = EXP2(-acc[1][r]);
            e_g[r] = EXP2(-acc[2][r]); e_o[r] = EXP2(-acc[3][r]);
        } else {
            e_i[r] = __expf(-acc[0][r]); e_f[r] = __expf(-acc[1][r]);
            e_g[r] = __expf(-2.0f * acc[2][r]); e_o[r] = __expf(-acc[3][r]);
        }
    }
    f32x4 d_i = e_i + 1.0f, d_f = e_f + 1.0f, d_g = e_g + 1.0f, d_o = e_o + 1.0f;
    f32x4 pif = d_i * d_f, pgo = d_g * d_o, pr = pif * pgo;
    f32x4 rr;
    #pragma unroll
    for (int r = 0; r < 4; ++r) rr[r] = __builtin_amdgcn_rcpf(pr[r]);
    f32x4 rif = rr * pgo, rgo = rr * pif;
    f32x4 s_i = rif * d_f, s_f = rif * d_i;
    f32x4 t_g = 2.0f * (rgo * d_o) - 1.0f;
    f32x4 s_o = rgo * d_g;
    f32x4 cn = s_f * creg + s_i * t_g;
    creg = cn;
    f32x4 ec;
    #pragma unroll
    for (int r = 0; r < 4; ++r) ec[r] = EXP2(cn[r] * -2.885390082f);
    f32x4 dc = ec + 1.0f;
    float p01 = dc[0] * dc[1], p23 = dc[2] * dc[3];
    float r2  = __builtin_amdgcn_rcpf(p01 * p23);
    float q01 = r2 * p23, q23 = r2 * p01;
    f32x4 tc;
    tc[0] = 2.0f * (q01 * dc[1]) - 1.0f;
    tc[1] = 2.0f * (q01 * dc[0]) - 1.0f;
    tc[2] = 2.0f * (q23 * dc[3]) - 1.0f;
    tc[3] = 2.0f * (q23 * dc[2]) - 1.0f;
    f32x4 h = s_o * tc;
    bf16x4 hv;
    hv[0] = (bf16_t)h[0]; hv[1] = (bf16_t)h[1];
    hv[2] = (bf16_t)h[2]; hv[3] = (bf16_t)h[3];
    return hv;
}

// ============== prep: fp32 -> bf16 bulk convert ==============
__global__ __launch_bounds__(256) void cvt_bf16_kernel(
    const float* __restrict__ src, bf16_t* __restrict__ dst, int n8)
{
    int i = blockIdx.x * 256 + threadIdx.x;
    if (i < n8) *(bf16x8*)(dst + (size_t)i * 8) = load8f(src + (size_t)i * 8);
}

// weights: scale by log2e (2*log2e for g-gate rows) BEFORE the single bf16
// rounding -> same rounding-error magnitude as unscaled conversion.
__global__ __launch_bounds__(256) void cvt_w_kernel(
    const float* __restrict__ src, bf16_t* __restrict__ dst, int n8)
{
    int i = blockIdx.x * 256 + threadIdx.x;
    if (i >= n8) return;
    int row  = (i >> 3) & 255;           // 8 elems never cross a row (64 % 8 == 0)
    int gate = row >> 6;
    float sc = (gate == 2) ? 2.885390082f : 1.442695041f;
    const float* p = src + (size_t)i * 8;
    f32x4 a = *(const f32x4*)p;
    f32x4 b = *(const f32x4*)(p + 4);
    bf16x8 r;
    r[0] = (bf16_t)(a[0]*sc); r[1] = (bf16_t)(a[1]*sc);
    r[2] = (bf16_t)(a[2]*sc); r[3] = (bf16_t)(a[3]*sc);
    r[4] = (bf16_t)(b[0]*sc); r[5] = (bf16_t)(b[1]*sc);
    r[6] = (bf16_t)(b[2]*sc); r[7] = (bf16_t)(b[3]*sc);
    *(bf16x8*)(dst + (size_t)i * 8) = r;
}

// ====== kernel 1: per-(tile,head) 2-layer LSTM, layer-split waves ======
// 512 threads: waves 0-3 layer0, waves 4-7 layer1, pipelined l0[t] || l1[t-1].
// MTP=32 nodes/block: each wave runs two independent 16-node halves/phase.
template<bool PREP>
__global__ __launch_bounds__(512, 3) void lstm_pipe_kernel(
    const float* __restrict__ xg,   // (T, N, 64) fp32
    const bf16_t* __restrict__ xbf, // (T, N, 64) bf16 (PREP)
    const float* __restrict__ Wih,  // (2, 8, 256, 64)
    const float* __restrict__ Whh,  // (2, 8, 256, 64)
    const bf16_t* __restrict__ wbf, // [Wih | Whh] bf16, pre-scaled (PREP)
    const float* __restrict__ bih,  // (2, 8, 256)
    const float* __restrict__ bhh,  // (2, 8, 256)
    const float* __restrict__ h0g,  // (8, 2, N, 64)
    const float* __restrict__ c0g,  // (8, 2, N, 64)
    bf16_t* __restrict__ hsw)       // (96, N, 64) channel-major hs
{
    __shared__ __align__(16) bf16_t h0A[2][MTP][LDSP];     // layer0 h dbuf (9.2KB)
    __shared__ __align__(16) bf16_t h1A[2][MTP][LDSP];     // layer1 h dbuf (9.2KB)
    __shared__ __align__(16) float  biasLds[2][4][4][16];  // [layer][wq][gate][gc]

    const int tid  = threadIdx.x;
    const int w    = tid >> 6;
    const int lane = tid & 63;
    const int quad = lane >> 4;
    const int col  = lane & 15;
    const int lw   = w >> 2;        // layer this wave serves
    const int wq   = w & 3;         // gate n-tile group within the layer
    const int a    = blockIdx.x & (NHEADS - 1);
    const int nb   = (blockIdx.x >> 3) * MTP;

    // ---- h0 init: layer0 -> h0A[0], layer1 -> h1A[1] ----
    {
        int e    = tid * 8;                    // 4096 elems = 2 layers x 2048
        int l    = e >> 11;
        int node = (e >> 6) & (MTP - 1);
        int hh   = e & (HD - 1);
        bf16x8 v = load8f(h0g + (((size_t)a * 2 + l) * NNODES + nb + node) * HD + hh);
        if (l == 0) *(bf16x8*)&h0A[0][node][hh] = v;
        else        *(bf16x8*)&h1A[1][node][hh] = v;
    }
    // ---- bias -> LDS (scaled to exp2 domain for PREP) ----
    {
        int l   = tid >> 8;
        int r   = tid & 255;
        int wqi = r >> 6;
        int nii = (r >> 4) & 3;
        int gc  = r & 15;
        int off = (l * NHEADS + a) * 256 + nii * 64 + wqi * 16 + gc;
        float sc = PREP ? (nii == 2 ? 2.885390082f : 1.442695041f) : 1.0f;
        biasLds[l][wqi][nii][gc] = (bih[off] + bhh[off]) * sc;
    }

    // ---- this wave's layer weights, register-resident ----
    bf16x8 wA[4][2], wB[4][2];      // [gate i/f/g/o][kfrag]; A=W_ih, B=W_hh
    #pragma unroll
    for (int ni = 0; ni < 4; ++ni)
        #pragma unroll
        for (int kf = 0; kf < 2; ++kf) {
            size_t off = (((size_t)lw * NHEADS + a) * 256 + (4 * ni + wq) * 16 + col) * HD
                       + kf * 32 + quad * 8;
            if (PREP) {
                wA[ni][kf] = *(const bf16x8*)(wbf + off);
                wB[ni][kf] = *(const bf16x8*)(wbf + WIH_ELEMS + off);
            } else {
                wA[ni][kf] = load8f(Wih + off);
                wB[ni][kf] = load8f(Whh + off);
            }
        }
    // cell state: half0 = node col, half1 = node col+16, hcols wq*16+quad*4..+3
    f32x4 cr0, cr1;
    {
        const float* cb = c0g + (((size_t)a * 2 + lw) * NNODES + nb) * HD
                        + wq * 16 + quad * 4;
        cr0 = *(const f32x4*)(cb + (size_t)col * HD);
        cr1 = *(const f32x4*)(cb + (size_t)(col + 16) * HD);
    }
    __syncthreads();

    int cur = 0;
    #pragma unroll 1
    for (int p = 0; p <= T_LEN; ++p) {
        if (lw == 0) {
            if (p < T_LEN) {
                // ---- x fragments straight from global (L3-resident) ----
                bf16x8 x00, x01, x10, x11;
                if (PREP) {
                    const bf16_t* xr = xbf + ((size_t)p * NNODES + nb) * HD + quad * 8;
                    x00 = *(const bf16x8*)(xr + (size_t)col * HD);
                    x01 = *(const bf16x8*)(xr + (size_t)col * HD + 32);
                    x10 = *(const bf16x8*)(xr + (size_t)(col + 16) * HD);
                    x11 = *(const bf16x8*)(xr + (size_t)(col + 16) * HD + 32);
                } else {
                    const float* xr = xg + ((size_t)p * NNODES + nb) * HD + quad * 8;
                    x00 = load8f(xr + (size_t)col * HD);
                    x01 = load8f(xr + (size_t)col * HD + 32);
                    x10 = load8f(xr + (size_t)(col + 16) * HD);
                    x11 = load8f(xr + (size_t)(col + 16) * HD + 32);
                }
                const bf16_t* H = &h0A[cur][0][0];
                const int r0 = col * LDSP + quad * 8;
                const int r1 = (col + 16) * LDSP + quad * 8;
                bf16x8 h00 = *(const bf16x8*)(H + r0);
                bf16x8 h01 = *(const bf16x8*)(H + r0 + 32);
                bf16x8 h10 = *(const bf16x8*)(H + r1);
                bf16x8 h11 = *(const bf16x8*)(H + r1 + 32);
                f32x4 acc0[4], acc1[4];
                #pragma unroll
                for (int ni = 0; ni < 4; ++ni) {
                    f32x4 z = *(const f32x4*)&biasLds[0][wq][ni][quad * 4];
                    z = MFMA16(wB[ni][0], h00, z);      // LDS operands first
                    z = MFMA16(wB[ni][1], h01, z);
                    z = MFMA16(wA[ni][0], x00, z);      // global x arrives by now
                    acc0[ni] = MFMA16(wA[ni][1], x01, z);
                }
                #pragma unroll
                for (int ni = 0; ni < 4; ++ni) {
                    f32x4 z = *(const f32x4*)&biasLds[0][wq][ni][quad * 4];
                    z = MFMA16(wB[ni][0], h10, z);
                    z = MFMA16(wB[ni][1], h11, z);
                    z = MFMA16(wA[ni][0], x10, z);
                    acc1[ni] = MFMA16(wA[ni][1], x11, z);
                }
                bf16_t* D = &h0A[cur ^ 1][0][0];
                bf16x4 hv0 = lstm_pointwise_v<PREP>(acc0, cr0);
                *(bf16x4*)(D + col * LDSP + wq * 16 + quad * 4) = hv0;
                bf16x4 hv1 = lstm_pointwise_v<PREP>(acc1, cr1);
                *(bf16x4*)(D + (col + 16) * LDSP + wq * 16 + quad * 4) = hv1;
            }
        } else {
            if (p >= 1) {
                const bf16_t* P = &h0A[cur][0][0];    // h_l0[p-1]
                const bf16_t* Q = &h1A[cur][0][0];    // h_l1[p-2]
                const int r0 = col * LDSP + quad * 8;
                const int r1 = (col + 16) * LDSP + quad * 8;
                bf16x8 p00 = *(const bf16x8*)(P + r0);
                bf16x8 p01 = *(const bf16x8*)(P + r0 + 32);
                bf16x8 q00 = *(const bf16x8*)(Q + r0);
                bf16x8 q01 = *(const bf16x8*)(Q + r0 + 32);
                bf16x8 p10 = *(const bf16x8*)(P + r1);
                bf16x8 p11 = *(const bf16x8*)(P + r1 + 32);
                bf16x8 q10 = *(const bf16x8*)(Q + r1);
                bf16x8 q11 = *(const bf16x8*)(Q + r1 + 32);
                f32x4 acc0[4], acc1[4];
                #pragma unroll
                for (int ni = 0; ni < 4; ++ni) {
                    f32x4 z = *(const f32x4*)&biasLds[1][wq][ni][quad * 4];
                    z = MFMA16(wA[ni][0], p00, z);
                    z = MFMA16(wA[ni][1], p01, z);
                    z = MFMA16(wB[ni][0], q00, z);
                    acc0[ni] = MFMA16(wB[ni][1], q01, z);
                }
                #pragma unroll
                for (int ni = 0; ni < 4; ++ni) {
                    f32x4 z = *(const f32x4*)&biasLds[1][wq][ni][quad * 4];
                    z = MFMA16(wA[ni][0], p10, z);
                    z = MFMA16(wA[ni][1], p11, z);
                    z = MFMA16(wB[ni][0], q10, z);
                    acc1[ni] = MFMA16(wB[ni][1], q11, z);
                }
                bf16_t* D = &h1A[cur ^ 1][0][0];
                bf16_t* hb = hsw + ((size_t)(a * T_LEN + (p - 1)) * NNODES + nb) * HD
                           + wq * 16 + quad * 4;
                bf16x4 hv0 = lstm_pointwise_v<PREP>(acc0, cr0);
                *(bf16x4*)(D + col * LDSP + wq * 16 + quad * 4) = hv0;
                *(bf16x4*)(hb + (size_t)col * HD) = hv0;
                bf16x4 hv1 = lstm_pointwise_v<PREP>(acc1, cr1);
                *(bf16x4*)(D + (col + 16) * LDSP + wq * 16 + quad * 4) = hv1;
                *(bf16x4*)(hb + (size_t)(col + 16) * HD) = hv1;
            }
        }
        __syncthreads();
        cur ^= 1;
    }
}

// ================= kernel 2: 96 -> 12 channel mix =================
__global__ __launch_bounds__(256) void conv_reduce_kernel(
    const bf16_t* __restrict__ hsw,  // (96, N, 64)
    const float* __restrict__ cwg,   // (12, 96)
    const float* __restrict__ cbg,   // (12)
    float* __restrict__ outg)        // (12, N, 64)
{
    int flat = blockIdx.x * 256 + threadIdx.x;   // N*16 threads
    int n  = flat >> 4;
    int h4 = (flat & 15) * 4;
    f32x4 acc[T_LEN];
    #pragma unroll
    for (int o = 0; o < T_LEN; ++o) {
        float b = cbg[o];
        acc[o][0] = b; acc[o][1] = b; acc[o][2] = b; acc[o][3] = b;
    }
    const bf16_t* src = hsw + (size_t)n * HD + h4;
    #pragma unroll 6
    for (int c = 0; c < NHEADS * T_LEN; ++c) {
        bf16x4 hv = *(const bf16x4*)(src + (size_t)c * NNODES * HD);
        float h0 = (float)hv[0], h1 = (float)hv[1], h2 = (float)hv[2], h3 = (float)hv[3];
        #pragma unroll
        for (int o = 0; o < T_LEN; ++o) {
            float cv = cwg[o * (NHEADS * T_LEN) + c];
            acc[o][0] += cv * h0; acc[o][1] += cv * h1;
            acc[o][2] += cv * h2; acc[o][3] += cv * h3;
        }
    }
    #pragma unroll
    for (int o = 0; o < T_LEN; ++o)
        *(f32x4*)(outg + ((size_t)o * NNODES + n) * HD + h4) = acc[o];
}

// ============ fallback: R2's proven monolithic kernel (fp32 I/O) ============
struct SmemT {
    __align__(16) bf16_t xT[T_LEN][MT][LDSP];
    __align__(16) bf16_t hA[2][2][MT][LDSP];
    __align__(16) float  cwf[T_LEN][NHEADS * T_LEN];
    __align__(16) float  cbf[T_LEN];
};

__global__ __launch_bounds__(256) void lstm_mono_kernel(
    const float* __restrict__ xg, const float* __restrict__ Wih,
    const float* __restrict__ Whh, const float* __restrict__ bih,
    const float* __restrict__ bhh, const float* __restrict__ h0g,
    const float* __restrict__ c0g, const float* __restrict__ cwg,
    const float* __restrict__ cbg, float* __restrict__ outg)
{
    __shared__ SmemT s;
    const int tid  = threadIdx.x;
    const int w    = tid >> 6;
    const int lane = tid & 63;
    const int quad = lane >> 4;
    const int col  = lane & 15;
    const int nb   = blockIdx.x * MT;

    #pragma unroll
    for (int it = 0; it < 6; ++it) {
        int ci   = it * 256 + tid;
        int e    = ci * 8;
        int t    = e >> 10;
        int node = (e >> 6) & (MT - 1);
        int f    = e & (HD - 1);
        *(bf16x8*)&s.xT[t][node][f] =
            load8f(xg + ((size_t)t * NNODES + nb + node) * HD + f);
    }
    for (int i = tid; i < T_LEN * NHEADS * T_LEN; i += 256)
        s.cwf[i / 96][i % 96] = cwg[i];
    if (tid < T_LEN) s.cbf[tid] = cbg[tid];

    float conv_acc[T_LEN][4];
    #pragma unroll
    for (int o = 0; o < T_LEN; ++o)
        #pragma unroll
        for (int r = 0; r < 4; ++r) conv_acc[o][r] = 0.0f;

    #pragma unroll 1
    for (int a = 0; a < NHEADS; ++a) {
        bf16x8 wih[2][4][2], whh[2][4][2];
        #pragma unroll
        for (int l = 0; l < 2; ++l)
            #pragma unroll
            for (int ni = 0; ni < 4; ++ni)
                #pragma unroll
                for (int kf = 0; kf < 2; ++kf) {
                    size_t off = (((size_t)l * NHEADS + a) * 256 + (4 * ni + w) * 16 + col) * HD
                               + kf * 32 + quad * 8;
                    wih[l][ni][kf] = load8f(Wih + off);
                    whh[l][ni][kf] = load8f(Whh + off);
                }
        float bias[2][4];
        #pragma unroll
        for (int l = 0; l < 2; ++l)
            #pragma unroll
            for (int ni = 0; ni < 4; ++ni) {
                int off = (l * NHEADS + a) * 256 + ni * 64 + w * 16 + col;
                bias[l][ni] = bih[off] + bhh[off];
            }
        float creg[2][4];
        #pragma unroll
        for (int l = 0; l < 2; ++l)
            #pragma unroll
            for (int r = 0; r < 4; ++r)
                creg[l][r] = c0g[(((size_t)a * 2 + l) * NNODES + nb + quad * 4 + r) * HD
                                 + w * 16 + col];
        {
            int e    = tid * 8;
            int l    = e >> 10;
            int node = (e >> 6) & (MT - 1);
            int hh   = e & (HD - 1);
            *(bf16x8*)&s.hA[l][0][node][hh] =
                load8f(h0g + (((size_t)a * 2 + l) * NNODES + nb + node) * HD + hh);
        }
        __syncthreads();

        int cur = 0;
        #pragma unroll 1
        for (int t = 0; t < T_LEN; ++t) {
            bf16x8 xa0 = *(const bf16x8*)&s.xT[t][col][quad * 8];
            bf16x8 xa1 = *(const bf16x8*)&s.xT[t][col][32 + quad * 8];
            bf16x8 ha0 = *(const bf16x8*)&s.hA[0][cur][col][quad * 8];
            bf16x8 ha1 = *(const bf16x8*)&s.hA[0][cur][col][32 + quad * 8];
            f32x4 acc[4];
            #pragma unroll
            for (int ni = 0; ni < 4; ++ni) {
                f32x4 z = {0.f, 0.f, 0.f, 0.f};
                z = MFMA16(xa0, wih[0][ni][0], z);
                z = MFMA16(xa1, wih[0][ni][1], z);
                z = MFMA16(ha0, whh[0][ni][0], z);
                z = MFMA16(ha1, whh[0][ni][1], z);
                acc[ni] = z;
            }
            #pragma unroll
            for (int r = 0; r < 4; ++r) {
                float ig = fast_sigmoid(acc[0][r] + bias[0][0]);
                float fg = fast_sigmoid(acc[1][r] + bias[0][1]);
                float gg = fast_tanh   (acc[2][r] + bias[0][2]);
                float og = fast_sigmoid(acc[3][r] + bias[0][3]);
                float cn = fg * creg[0][r] + ig * gg;
                creg[0][r] = cn;
                s.hA[0][cur ^ 1][quad * 4 + r][w * 16 + col] = (bf16_t)(og * fast_tanh(cn));
            }
            __syncthreads();
            bf16x8 pa0 = *(const bf16x8*)&s.hA[0][cur ^ 1][col][quad * 8];
            bf16x8 pa1 = *(const bf16x8*)&s.hA[0][cur ^ 1][col][32 + quad * 8];
            bf16x8 qa0 = *(const bf16x8*)&s.hA[1][cur][col][quad * 8];
            bf16x8 qa1 = *(const bf16x8*)&s.hA[1][cur][col][32 + quad * 8];
            #pragma unroll
            for (int ni = 0; ni < 4; ++ni) {
                f32x4 z = {0.f, 0.f, 0.f, 0.f};
                z = MFMA16(pa0, wih[1][ni][0], z);
                z = MFMA16(pa1, wih[1][ni][1], z);
                z = MFMA16(qa0, whh[1][ni][0], z);
                z = MFMA16(qa1, whh[1][ni][1], z);
                acc[ni] = z;
            }
            float hn[4];
            #pragma unroll
            for (int r = 0; r < 4; ++r) {
                float ig = fast_sigmoid(acc[0][r] + bias[1][0]);
                float fg = fast_sigmoid(acc[1][r] + bias[1][1]);
                float gg = fast_tanh   (acc[2][r] + bias[1][2]);
                float og = fast_sigmoid(acc[3][r] + bias[1][3]);
                float cn = fg * creg[1][r] + ig * gg;
                creg[1][r] = cn;
                hn[r] = og * fast_tanh(cn);
                s.hA[1][cur ^ 1][quad * 4 + r][w * 16 + col] = (bf16_t)hn[r];
            }
            #pragma unroll
            for (int o = 0; o < T_LEN; ++o) {
                float cv = s.cwf[o][a * T_LEN + t];
                #pragma unroll
                for (int r = 0; r < 4; ++r) conv_acc[o][r] += cv * hn[r];
            }
            __syncthreads();
            cur ^= 1;
        }
    }
    #pragma unroll
    for (int o = 0; o < T_LEN; ++o)
        #pragma unroll
        for (int r = 0; r < 4; ++r)
            outg[((size_t)o * NNODES + nb + quad * 4 + r) * HD + w * 16 + col] =
                conv_acc[o][r] + s.cbf[o];
}

extern "C" void kernel_launch(void* const* d_in, const int* in_sizes, int n_in,
                              void* d_out, int out_size, void* d_ws, size_t ws_size,
                              hipStream_t stream) {
    (void)in_sizes; (void)n_in; (void)out_size;
    const float* x   = (const float*)d_in[0];
    const float* Wih = (const float*)d_in[1];
    const float* Whh = (const float*)d_in[2];
    const float* bih = (const float*)d_in[3];
    const float* bhh = (const float*)d_in[4];
    const float* h0  = (const float*)d_in[5];
    const float* c0  = (const float*)d_in[6];
    const float* cw  = (const float*)d_in[7];
    const float* cb  = (const float*)d_in[8];
    const size_t hs_bytes = (size_t)NHEADS * T_LEN * NNODES * HD * sizeof(bf16_t);
    const size_t x_bytes  = (size_t)T_LEN * NNODES * HD * sizeof(bf16_t);
    const size_t w_bytes  = (size_t)2 * WIH_ELEMS * sizeof(bf16_t);
    if (ws_size >= hs_bytes + x_bytes + w_bytes) {
        bf16_t* hs  = (bf16_t*)d_ws;
        bf16_t* xbf = (bf16_t*)((char*)d_ws + hs_bytes);
        bf16_t* wbf = (bf16_t*)((char*)d_ws + hs_bytes + x_bytes);
        const int n8x = T_LEN * NNODES * HD / 8;
        const int n8w = WIH_ELEMS / 8;
        cvt_bf16_kernel<<<dim3(n8x / 256), dim3(256), 0, stream>>>(x, xbf, n8x);
        cvt_w_kernel<<<dim3((n8w + 255) / 256), dim3(256), 0, stream>>>(Wih, wbf, n8w);
        cvt_w_kernel<<<dim3((n8w + 255) / 256), dim3(256), 0, stream>>>(Whh, wbf + WIH_ELEMS, n8w);
        lstm_pipe_kernel<true><<<dim3((NNODES / MTP) * NHEADS), dim3(512), 0, stream>>>(
            x, xbf, Wih, Whh, wbf, bih, bhh, h0, c0, hs);
        conv_reduce_kernel<<<dim3(NNODES * 16 / 256), dim3(256), 0, stream>>>(
            hs, cw, cb, (float*)d_out);
    } else if (ws_size >= hs_bytes) {
        bf16_t* hs = (bf16_t*)d_ws;
        lstm_pipe_kernel<false><<<dim3((NNODES / MTP) * NHEADS), dim3(512), 0, stream>>>(
            x, nullptr, Wih, Whh, nullptr, bih, bhh, h0, c0, hs);
        conv_reduce_kernel<<<dim3(NNODES * 16 / 256), dim3(256), 0, stream>>>(
            hs, cw, cb, (float*)d_out);
    } else {
        lstm_mono_kernel<<<dim3(NNODES / MT), dim3(256), 0, stream>>>(
            x, Wih, Whh, bih, bhh, h0, c0, cw, cb, (float*)d_out);
    }
}

// Round 5
// 492.267 us; speedup vs baseline: 1.1746x; 1.1746x over previous
//
#include <hip/hip_runtime.h>
#include <hip/hip_bf16.h>

// LSTMblock: 2-layer, 8-head LSTM (H=F=64, T=12) over N=16384 nodes, then
// 1x1 conv mixing (head,t) channels (96 -> 12). fp32 I/O, bf16 MFMA, fp32 cell.
//
// R9: R6 (-VALU) flat, R7 (-vmcnt drain) -3%, R8 (+ILP, -occupancy) worse.
// Diagnosis: latency-bound on the post-barrier dependent chain, 16 waves in
// lockstep: ds_read(120) -> 4-deep MFMA(80) -> pointwise(~330, the shared-rcp
// trick LENGTHENS the chain to save throughput) -> write -> barrier.
// Changes vs R7 (structure + occupancy preserved):
//  (1) independent-rcp pointwise: sig = rcp(1+exp2(-g)) per gate; chain
//      ~330 -> ~120 cyc at +19 trans ops/phase on the idle trans pipe.
//  (2) l0 x-frag register prefetch (x is t-static, not recurrence-coupled);
//      MFMA order x,x,h,h so x-MFMAs issue under the post-barrier h-read.
//      (h0A/h1H reads CANNOT hoist: written in the current phase.)
//  (3) hs layout -> node-major (N, 96, 64): epilogue writes each node's
//      12x64 slice contiguously; conv reads each node as a sequential 12KB
//      stream (was 96 loads at 2MB stride -> ~1.6TB/s effective).
//  (4) __launch_bounds__(512,4) keeps arch VGPR <= 64 (+64 AGPR weights
//      = 128/wave = 4 waves/SIMD, 2 blocks/CU with 62.8KB LDS).
//
// MFMA v_mfma_f32_16x16x32_bf16 lane mapping (m89/m120-verified):
//   A[m][k]: lane(quad,col) reg j holds A[m=col][k=quad*8+j]
//   B[k][n]: lane reg j holds B[k=quad*8+j][n=col]
//   D[m][n]: lane reg r holds D[m=quad*4+r][n=col]
// Swapped form D = W*h^T: lane holds gates for node=col at 4 consecutive
// gate-cols (wq*16 + quad*4 + r); h-write is one ds_write_b64.

#define T_LEN 12
#define NHEADS 8
#define HD 64
#define NNODES 16384
#define MT 16
#define LDSP 72
#define NCH (NHEADS * T_LEN)                   // 96 hs channels
#define WIH_ELEMS (2 * NHEADS * 4 * HD * HD)   // 262144 elems per weight tensor

typedef __bf16 bf16_t;
typedef __attribute__((ext_vector_type(2))) __bf16 bf16x2;
typedef __attribute__((ext_vector_type(4))) __bf16 bf16x4;
typedef __attribute__((ext_vector_type(8))) __bf16 bf16x8;
typedef __attribute__((ext_vector_type(4))) float f32x4;

#define MFMA16(a, b, c) __builtin_amdgcn_mfma_f32_16x16x32_bf16((a), (b), (c), 0, 0, 0)

#if __has_builtin(__builtin_amdgcn_exp2f)
#define EXP2(x) __builtin_amdgcn_exp2f(x)
#else
#define EXP2(x) exp2f(x)
#endif

__device__ __forceinline__ float fast_sigmoid(float v) {
    return __builtin_amdgcn_rcpf(1.0f + __expf(-v));
}
__device__ __forceinline__ float fast_tanh(float v) {
    return 2.0f * __builtin_amdgcn_rcpf(1.0f + __expf(-2.0f * v)) - 1.0f;
}

__device__ __forceinline__ bf16x8 load8f(const float* p) {
    f32x4 a = *(const f32x4*)p;
    f32x4 b = *(const f32x4*)(p + 4);
    bf16x8 r;
    r[0] = (bf16_t)a[0]; r[1] = (bf16_t)a[1]; r[2] = (bf16_t)a[2]; r[3] = (bf16_t)a[3];
    r[4] = (bf16_t)b[0]; r[5] = (bf16_t)b[1]; r[6] = (bf16_t)b[2]; r[7] = (bf16_t)b[3];
    return r;
}
__device__ __forceinline__ bf16x4 load4f(const float* p) {
    f32x4 a = *(const f32x4*)p;
    bf16x4 r;
    r[0] = (bf16_t)a[0]; r[1] = (bf16_t)a[1]; r[2] = (bf16_t)a[2]; r[3] = (bf16_t)a[3];
    return r;
}

__device__ __forceinline__ f32x4 exp2n4(f32x4 v) {   // exp2(-v), per element
    f32x4 r;
    #pragma unroll
    for (int i = 0; i < 4; ++i) r[i] = EXP2(-v[i]);
    return r;
}
__device__ __forceinline__ f32x4 rcp4(f32x4 v) {
    f32x4 r;
    #pragma unroll
    for (int i = 0; i < 4; ++i) r[i] = __builtin_amdgcn_rcpf(v[i]);
    return r;
}

// Gate pointwise, LATENCY-OPTIMIZED: independent rcp per gate (2-trans-deep
// chain: exp2 -> add -> rcp -> fma). SC=true: pre-acts pre-scaled by log2e
// (2log2e for g) at weight-prep time.
template<bool SC>
__device__ __forceinline__ bf16x4 lstm_pointwise_v(const f32x4* acc, f32x4& creg) {
    f32x4 gi = acc[0], gf = acc[1], gg = acc[2], go = acc[3];
    if (!SC) {
        gi = gi * 1.442695041f; gf = gf * 1.442695041f;
        gg = gg * 2.885390082f; go = go * 1.442695041f;
    }
    f32x4 si = rcp4(exp2n4(gi) + 1.0f);
    f32x4 sf = rcp4(exp2n4(gf) + 1.0f);
    f32x4 tg = 2.0f * rcp4(exp2n4(gg) + 1.0f) - 1.0f;
    f32x4 so = rcp4(exp2n4(go) + 1.0f);
    f32x4 cn = sf * creg + si * tg;
    creg = cn;
    f32x4 tc = 2.0f * rcp4(exp2n4(cn * 2.885390082f) + 1.0f) - 1.0f;
    f32x4 h  = so * tc;
    bf16x4 hv;
    hv[0] = (bf16_t)h[0]; hv[1] = (bf16_t)h[1];
    hv[2] = (bf16_t)h[2]; hv[3] = (bf16_t)h[3];
    return hv;
}

// ============== prep: fp32 -> bf16 bulk convert ==============
__global__ __launch_bounds__(256) void cvt_bf16_kernel(
    const float* __restrict__ src, bf16_t* __restrict__ dst, int n8)
{
    int i = blockIdx.x * 256 + threadIdx.x;
    if (i < n8) *(bf16x8*)(dst + (size_t)i * 8) = load8f(src + (size_t)i * 8);
}

// weights: scale by log2e (2*log2e for g-gate rows) BEFORE the single bf16
// rounding -> same rounding-error magnitude as unscaled conversion.
__global__ __launch_bounds__(256) void cvt_w_kernel(
    const float* __restrict__ src, bf16_t* __restrict__ dst, int n8)
{
    int i = blockIdx.x * 256 + threadIdx.x;
    if (i >= n8) return;
    int row  = (i >> 3) & 255;           // 8 elems never cross a row (64 % 8 == 0)
    int gate = row >> 6;
    float sc = (gate == 2) ? 2.885390082f : 1.442695041f;
    const float* p = src + (size_t)i * 8;
    f32x4 a = *(const f32x4*)p;
    f32x4 b = *(const f32x4*)(p + 4);
    bf16x8 r;
    r[0] = (bf16_t)(a[0]*sc); r[1] = (bf16_t)(a[1]*sc);
    r[2] = (bf16_t)(a[2]*sc); r[3] = (bf16_t)(a[3]*sc);
    r[4] = (bf16_t)(b[0]*sc); r[5] = (bf16_t)(b[1]*sc);
    r[6] = (bf16_t)(b[2]*sc); r[7] = (bf16_t)(b[3]*sc);
    *(bf16x8*)(dst + (size_t)i * 8) = r;
}

// ====== kernel 1: per-(tile,head) 2-layer LSTM, layer-split waves ======
// 512 threads: waves 0-3 layer0, waves 4-7 layer1, pipelined l0[t] || l1[t-1].
// NO global memory ops inside the t-loop; h1 history in LDS; node-major
// bulk hs store after the final barrier.
template<bool PREP>
__global__ __launch_bounds__(512, 4) void lstm_pipe_kernel(
    const float* __restrict__ xg,   // (T, N, 64) fp32
    const bf16_t* __restrict__ xbf, // (T, N, 64) bf16 (PREP)
    const float* __restrict__ Wih,  // (2, 8, 256, 64)
    const float* __restrict__ Whh,  // (2, 8, 256, 64)
    const bf16_t* __restrict__ wbf, // [Wih | Whh] bf16, pre-scaled (PREP)
    const float* __restrict__ bih,  // (2, 8, 256)
    const float* __restrict__ bhh,  // (2, 8, 256)
    const float* __restrict__ h0g,  // (8, 2, N, 64)
    const float* __restrict__ c0g,  // (8, 2, N, 64)
    bf16_t* __restrict__ hsw)       // (N, 96, 64) NODE-major hs
{
    __shared__ __align__(16) bf16_t xT[T_LEN][MT][LDSP];       // x tile (27.6KB)
    __shared__ __align__(16) bf16_t h0A[2][MT][LDSP];          // layer0 h dbuf (4.6KB)
    __shared__ __align__(16) bf16_t h1H[T_LEN + 1][MT][LDSP];  // layer1 h history (30KB)
    __shared__ __align__(16) float  biasLds[2][4][4][16];      // [layer][wq][gate][gc]

    const int tid  = threadIdx.x;
    const int w    = tid >> 6;
    const int lane = tid & 63;
    const int quad = lane >> 4;
    const int col  = lane & 15;
    const int lw   = w >> 2;        // layer this wave serves
    const int wq   = w & 3;         // gate n-tile group within the layer
    const int a    = blockIdx.x & (NHEADS - 1);
    const int nb   = (blockIdx.x >> 3) * MT;

    // ---- x tile -> LDS ----
    #pragma unroll
    for (int it = 0; it < 3; ++it) {
        int e    = (it * 512 + tid) * 8;
        int t    = e >> 10;
        int node = (e >> 6) & (MT - 1);
        int f    = e & (HD - 1);
        bf16x8 v;
        if (PREP) v = *(const bf16x8*)(xbf + ((size_t)t * NNODES + nb + node) * HD + f);
        else      v = load8f(xg + ((size_t)t * NNODES + nb + node) * HD + f);
        *(bf16x8*)&xT[t][node][f] = v;
    }
    // ---- h0 init: layer0 -> h0A[0], layer1 -> h1H[0] ----
    {
        int e    = tid * 4;
        int l    = e >> 10;
        int node = (e >> 6) & (MT - 1);
        int hh   = e & (HD - 1);
        bf16x4 v = load4f(h0g + (((size_t)a * 2 + l) * NNODES + nb + node) * HD + hh);
        if (l == 0) *(bf16x4*)&h0A[0][node][hh] = v;
        else        *(bf16x4*)&h1H[0][node][hh] = v;
    }
    // ---- bias -> LDS (scaled to exp2 domain for PREP) ----
    {
        int l   = tid >> 8;
        int r   = tid & 255;
        int wqi = r >> 6;
        int nii = (r >> 4) & 3;
        int gc  = r & 15;
        int off = (l * NHEADS + a) * 256 + nii * 64 + wqi * 16 + gc;
        float sc = PREP ? (nii == 2 ? 2.885390082f : 1.442695041f) : 1.0f;
        biasLds[l][wqi][nii][gc] = (bih[off] + bhh[off]) * sc;
    }

    // ---- this wave's layer weights, register-resident (64 regs) ----
    bf16x8 wA[4][2], wB[4][2];      // [gate i/f/g/o][kfrag]; A=W_ih, B=W_hh
    #pragma unroll
    for (int ni = 0; ni < 4; ++ni)
        #pragma unroll
        for (int kf = 0; kf < 2; ++kf) {
            size_t off = (((size_t)lw * NHEADS + a) * 256 + (4 * ni + wq) * 16 + col) * HD
                       + kf * 32 + quad * 8;
            if (PREP) {
                wA[ni][kf] = *(const bf16x8*)(wbf + off);
                wB[ni][kf] = *(const bf16x8*)(wbf + WIH_ELEMS + off);
            } else {
                wA[ni][kf] = load8f(Wih + off);
                wB[ni][kf] = load8f(Whh + off);
            }
        }
    // cell state for (node=col, hcol = wq*16 + quad*4 + r)
    f32x4 creg = *(const f32x4*)(c0g + (((size_t)a * 2 + lw) * NNODES + nb + col) * HD
                                 + wq * 16 + quad * 4);
    __syncthreads();

    const int ro = col * LDSP + quad * 8;
    // l0: prefetch phase-0 x fragments (t-static -> barrier-independent)
    bf16x8 px0, px1;
    if (lw == 0) {
        px0 = *(const bf16x8*)&xT[0][col][quad * 8];
        px1 = *(const bf16x8*)&xT[0][col][32 + quad * 8];
    }

    int cur = 0;
    #pragma unroll 1
    for (int p = 0; p <= T_LEN; ++p) {
        if (lw == 0) {
            if (p < T_LEN) {
                // post-barrier recurrent reads (cannot hoist)
                bf16x8 h0f = *(const bf16x8*)(&h0A[cur][0][0] + ro);
                bf16x8 h1f = *(const bf16x8*)(&h0A[cur][0][0] + ro + 32);
                f32x4 acc[4];
                #pragma unroll
                for (int ni = 0; ni < 4; ++ni) {
                    f32x4 z = *(const f32x4*)&biasLds[0][wq][ni][quad * 4];
                    z = MFMA16(wA[ni][0], px0, z);   // x MFMAs issue immediately
                    z = MFMA16(wA[ni][1], px1, z);
                    z = MFMA16(wB[ni][0], h0f, z);   // h arrives under x MFMAs
                    acc[ni] = MFMA16(wB[ni][1], h1f, z);
                }
                // prefetch next phase's x before the pointwise chain
                if (p + 1 < T_LEN) {
                    px0 = *(const bf16x8*)&xT[p + 1][col][quad * 8];
                    px1 = *(const bf16x8*)&xT[p + 1][col][32 + quad * 8];
                }
                bf16x4 hv = lstm_pointwise_v<PREP>(acc, creg);
                *(bf16x4*)(&h0A[cur ^ 1][0][0] + col * LDSP + wq * 16 + quad * 4) = hv;
            }
        } else {
            if (p >= 1) {
                const bf16_t* P = &h0A[cur][0][0];    // h_l0[p-1] (this phase's input)
                const bf16_t* Q = &h1H[p - 1][0][0];  // h_l1[p-2]
                bf16x8 p0f = *(const bf16x8*)(P + ro);
                bf16x8 p1f = *(const bf16x8*)(P + ro + 32);
                bf16x8 q0f = *(const bf16x8*)(Q + ro);
                bf16x8 q1f = *(const bf16x8*)(Q + ro + 32);
                f32x4 acc[4];
                #pragma unroll
                for (int ni = 0; ni < 4; ++ni) {
                    f32x4 z = *(const f32x4*)&biasLds[1][wq][ni][quad * 4];
                    z = MFMA16(wA[ni][0], p0f, z);
                    z = MFMA16(wA[ni][1], p1f, z);
                    z = MFMA16(wB[ni][0], q0f, z);
                    acc[ni] = MFMA16(wB[ni][1], q1f, z);
                }
                bf16x4 hv = lstm_pointwise_v<PREP>(acc, creg);
                *(bf16x4*)(&h1H[p][0][0] + col * LDSP + wq * 16 + quad * 4) = hv;
            }
        }
        __syncthreads();
        cur ^= 1;
    }

    // ---- epilogue: node-major bulk hs store ----
    // hsw layout (N, 96, 64); this block fills nodes nb..nb+15, channels
    // a*12..a*12+11. Per node: 12*64 bf16 = 1.5KB contiguous.
    {
        int node = tid >> 5;            // 16 nodes, 32 threads each
        int sub  = tid & 31;
        #pragma unroll
        for (int k = 0; k < 3; ++k) {
            int c8 = k * 32 + sub;      // 96 bf16x8-chunks per node
            int t  = c8 >> 3;
            int h8 = (c8 & 7) * 8;
            *(bf16x8*)(hsw + ((size_t)(nb + node) * NCH + a * T_LEN + t) * HD + h8) =
                *(const bf16x8*)&h1H[t + 1][node][h8];
        }
    }
}

// ================= kernel 2: 96 -> 12 channel mix =================
// hsw node-major: each thread streams its node's 12KB sequentially.
__global__ __launch_bounds__(256) void conv_reduce_kernel(
    const bf16_t* __restrict__ hsw,  // (N, 96, 64)
    const float* __restrict__ cwg,   // (12, 96)
    const float* __restrict__ cbg,   // (12)
    float* __restrict__ outg)        // (12, N, 64)
{
    int flat = blockIdx.x * 256 + threadIdx.x;   // N*16 threads
    int n  = flat >> 4;
    int h4 = (flat & 15) * 4;
    f32x4 acc[T_LEN];
    #pragma unroll
    for (int o = 0; o < T_LEN; ++o) {
        float b = cbg[o];
        acc[o][0] = b; acc[o][1] = b; acc[o][2] = b; acc[o][3] = b;
    }
    const bf16_t* src = hsw + (size_t)n * (NCH * HD) + h4;
    #pragma unroll 8
    for (int c = 0; c < NCH; ++c) {
        bf16x4 hv = *(const bf16x4*)(src + (size_t)c * HD);
        float h0 = (float)hv[0], h1 = (float)hv[1], h2 = (float)hv[2], h3 = (float)hv[3];
        #pragma unroll
        for (int o = 0; o < T_LEN; ++o) {
            float cv = cwg[o * NCH + c];
            acc[o][0] += cv * h0; acc[o][1] += cv * h1;
            acc[o][2] += cv * h2; acc[o][3] += cv * h3;
        }
    }
    #pragma unroll
    for (int o = 0; o < T_LEN; ++o)
        *(f32x4*)(outg + ((size_t)o * NNODES + n) * HD + h4) = acc[o];
}

// ============ fallback: R2's proven monolithic kernel (fp32 I/O) ============
struct SmemT {
    __align__(16) bf16_t xT[T_LEN][MT][LDSP];
    __align__(16) bf16_t hA[2][2][MT][LDSP];
    __align__(16) float  cwf[T_LEN][NCH];
    __align__(16) float  cbf[T_LEN];
};

__global__ __launch_bounds__(256) void lstm_mono_kernel(
    const float* __restrict__ xg, const float* __restrict__ Wih,
    const float* __restrict__ Whh, const float* __restrict__ bih,
    const float* __restrict__ bhh, const float* __restrict__ h0g,
    const float* __restrict__ c0g, const float* __restrict__ cwg,
    const float* __restrict__ cbg, float* __restrict__ outg)
{
    __shared__ SmemT s;
    const int tid  = threadIdx.x;
    const int w    = tid >> 6;
    const int lane = tid & 63;
    const int quad = lane >> 4;
    const int col  = lane & 15;
    const int nb   = blockIdx.x * MT;

    #pragma unroll
    for (int it = 0; it < 6; ++it) {
        int ci   = it * 256 + tid;
        int e    = ci * 8;
        int t    = e >> 10;
        int node = (e >> 6) & (MT - 1);
        int f    = e & (HD - 1);
        *(bf16x8*)&s.xT[t][node][f] =
            load8f(xg + ((size_t)t * NNODES + nb + node) * HD + f);
    }
    for (int i = tid; i < T_LEN * NCH; i += 256)
        s.cwf[i / 96][i % 96] = cwg[i];
    if (tid < T_LEN) s.cbf[tid] = cbg[tid];

    float conv_acc[T_LEN][4];
    #pragma unroll
    for (int o = 0; o < T_LEN; ++o)
        #pragma unroll
        for (int r = 0; r < 4; ++r) conv_acc[o][r] = 0.0f;

    #pragma unroll 1
    for (int a = 0; a < NHEADS; ++a) {
        bf16x8 wih[2][4][2], whh[2][4][2];
        #pragma unroll
        for (int l = 0; l < 2; ++l)
            #pragma unroll
            for (int ni = 0; ni < 4; ++ni)
                #pragma unroll
                for (int kf = 0; kf < 2; ++kf) {
                    size_t off = (((size_t)l * NHEADS + a) * 256 + (4 * ni + w) * 16 + col) * HD
                               + kf * 32 + quad * 8;
                    wih[l][ni][kf] = load8f(Wih + off);
                    whh[l][ni][kf] = load8f(Whh + off);
                }
        float bias[2][4];
        #pragma unroll
        for (int l = 0; l < 2; ++l)
            #pragma unroll
            for (int ni = 0; ni < 4; ++ni) {
                int off = (l * NHEADS + a) * 256 + ni * 64 + w * 16 + col;
                bias[l][ni] = bih[off] + bhh[off];
            }
        float creg[2][4];
        #pragma unroll
        for (int l = 0; l < 2; ++l)
            #pragma unroll
            for (int r = 0; r < 4; ++r)
                creg[l][r] = c0g[(((size_t)a * 2 + l) * NNODES + nb + quad * 4 + r) * HD
                                 + w * 16 + col];
        {
            int e    = tid * 8;
            int l    = e >> 10;
            int node = (e >> 6) & (MT - 1);
            int hh   = e & (HD - 1);
            *(bf16x8*)&s.hA[l][0][node][hh] =
                load8f(h0g + (((size_t)a * 2 + l) * NNODES + nb + node) * HD + hh);
        }
        __syncthreads();

        int cur = 0;
        #pragma unroll 1
        for (int t = 0; t < T_LEN; ++t) {
            bf16x8 xa0 = *(const bf16x8*)&s.xT[t][col][quad * 8];
            bf16x8 xa1 = *(const bf16x8*)&s.xT[t][col][32 + quad * 8];
            bf16x8 ha0 = *(const bf16x8*)&s.hA[0][cur][col][quad * 8];
            bf16x8 ha1 = *(const bf16x8*)&s.hA[0][cur][col][32 + quad * 8];
            f32x4 acc[4];
            #pragma unroll
            for (int ni = 0; ni < 4; ++ni) {
                f32x4 z = {0.f, 0.f, 0.f, 0.f};
                z = MFMA16(xa0, wih[0][ni][0], z);
                z = MFMA16(xa1, wih[0][ni][1], z);
                z = MFMA16(ha0, whh[0][ni][0], z);
                z = MFMA16(ha1, whh[0][ni][1], z);
                acc[ni] = z;
            }
            #pragma unroll
            for (int r = 0; r < 4; ++r) {
                float ig = fast_sigmoid(acc[0][r] + bias[0][0]);
                float fg = fast_sigmoid(acc[1][r] + bias[0][1]);
                float gg = fast_tanh   (acc[2][r] + bias[0][2]);
                float og = fast_sigmoid(acc[3][r] + bias[0][3]);
                float cn = fg * creg[0][r] + ig * gg;
                creg[0][r] = cn;
                s.hA[0][cur ^ 1][quad * 4 + r][w * 16 + col] = (bf16_t)(og * fast_tanh(cn));
            }
            __syncthreads();
            bf16x8 pa0 = *(const bf16x8*)&s.hA[0][cur ^ 1][col][quad * 8];
            bf16x8 pa1 = *(const bf16x8*)&s.hA[0][cur ^ 1][col][32 + quad * 8];
            bf16x8 qa0 = *(const bf16x8*)&s.hA[1][cur][col][quad * 8];
            bf16x8 qa1 = *(const bf16x8*)&s.hA[1][cur][col][32 + quad * 8];
            #pragma unroll
            for (int ni = 0; ni < 4; ++ni) {
                f32x4 z = {0.f, 0.f, 0.f, 0.f};
                z = MFMA16(pa0, wih[1][ni][0], z);
                z = MFMA16(pa1, wih[1][ni][1], z);
                z = MFMA16(qa0, whh[1][ni][0], z);
                z = MFMA16(qa1, whh[1][ni][1], z);
                acc[ni] = z;
            }
            float hn[4];
            #pragma unroll
            for (int r = 0; r < 4; ++r) {
                float ig = fast_sigmoid(acc[0][r] + bias[1][0]);
                float fg = fast_sigmoid(acc[1][r] + bias[1][1]);
                float gg = fast_tanh   (acc[2][r] + bias[1][2]);
                float og = fast_sigmoid(acc[3][r] + bias[1][3]);
                float cn = fg * creg[1][r] + ig * gg;
                creg[1][r] = cn;
                hn[r] = og * fast_tanh(cn);
                s.hA[1][cur ^ 1][quad * 4 + r][w * 16 + col] = (bf16_t)hn[r];
            }
            #pragma unroll
            for (int o = 0; o < T_LEN; ++o) {
                float cv = s.cwf[o][a * T_LEN + t];
                #pragma unroll
                for (int r = 0; r < 4; ++r) conv_acc[o][r] += cv * hn[r];
            }
            __syncthreads();
            cur ^= 1;
        }
    }
    #pragma unroll
    for (int o = 0; o < T_LEN; ++o)
        #pragma unroll
        for (int r = 0; r < 4; ++r)
            outg[((size_t)o * NNODES + nb + quad * 4 + r) * HD + w * 16 + col] =
                conv_acc[o][r] + s.cbf[o];
}

extern "C" void kernel_launch(void* const* d_in, const int* in_sizes, int n_in,
                              void* d_out, int out_size, void* d_ws, size_t ws_size,
                              hipStream_t stream) {
    (void)in_sizes; (void)n_in; (void)out_size;
    const float* x   = (const float*)d_in[0];
    const float* Wih = (const float*)d_in[1];
    const float* Whh = (const float*)d_in[2];
    const float* bih = (const float*)d_in[3];
    const float* bhh = (const float*)d_in[4];
    const float* h0  = (const float*)d_in[5];
    const float* c0  = (const float*)d_in[6];
    const float* cw  = (const float*)d_in[7];
    const float* cb  = (const float*)d_in[8];
    const size_t hs_bytes = (size_t)NCH * NNODES * HD * sizeof(bf16_t);
    const size_t x_bytes  = (size_t)T_LEN * NNODES * HD * sizeof(bf16_t);
    const size_t w_bytes  = (size_t)2 * WIH_ELEMS * sizeof(bf16_t);
    if (ws_size >= hs_bytes + x_bytes + w_bytes) {
        bf16_t* hs  = (bf16_t*)d_ws;
        bf16_t* xbf = (bf16_t*)((char*)d_ws + hs_bytes);
        bf16_t* wbf = (bf16_t*)((char*)d_ws + hs_bytes + x_bytes);
        const int n8x = T_LEN * NNODES * HD / 8;
        const int n8w = WIH_ELEMS / 8;
        cvt_bf16_kernel<<<dim3(n8x / 256), dim3(256), 0, stream>>>(x, xbf, n8x);
        cvt_w_kernel<<<dim3((n8w + 255) / 256), dim3(256), 0, stream>>>(Wih, wbf, n8w);
        cvt_w_kernel<<<dim3((n8w + 255) / 256), dim3(256), 0, stream>>>(Whh, wbf + WIH_ELEMS, n8w);
        lstm_pipe_kernel<true><<<dim3((NNODES / MT) * NHEADS), dim3(512), 0, stream>>>(
            x, xbf, Wih, Whh, wbf, bih, bhh, h0, c0, hs);
        conv_reduce_kernel<<<dim3(NNODES * 16 / 256), dim3(256), 0, stream>>>(
            hs, cw, cb, (float*)d_out);
    } else if (ws_size >= hs_bytes) {
        bf16_t* hs = (bf16_t*)d_ws;
        lstm_pipe_kernel<false><<<dim3((NNODES / MT) * NHEADS), dim3(512), 0, stream>>>(
            x, nullptr, Wih, Whh, nullptr, bih, bhh, h0, c0, hs);
        conv_reduce_kernel<<<dim3(NNODES * 16 / 256), dim3(256), 0, stream>>>(
            hs, cw, cb, (float*)d_out);
    } else {
        lstm_mono_kernel<<<dim3(NNODES / MT), dim3(256), 0, stream>>>(
            x, Wih, Whh, bih, bhh, h0, c0, cw, cb, (float*)d_out);
    }
}